// Round 2
// baseline (343.879 us; speedup 1.0000x reference)
//
#include <hip/hip_runtime.h>
#include <hip/hip_bf16.h>
#include <stdint.h>

#define B_DIM 64
#define S_DIM 512
#define K_DIM 1024   // F_IN
#define N_DIM 1024   // F_OUT
#define M_DIM (B_DIM * S_DIM)  // 32768

typedef __attribute__((ext_vector_type(8))) short short8;
typedef __attribute__((ext_vector_type(4))) float floatx4;

// ---------------------------------------------------------------------------
// Kernel 1: chunked EMA scan along S on x (fp32) fused with fp32->bf16.
// scan_S(x) @ W^T == scan_S(x @ W^T) (linearity), so we scan the GEMM input.
// alpha=0.5 forgets at 0.5^k: a 32-step warm-up re-start is exact to ~2^-32,
// so S=512 is split into 8 chunks of 64 -> 131072 threads (vs 65536 serial
// threads before = 4 waves/CU, which was latency-bound at ~1 TB/s).
// Each thread owns 4 consecutive features (float4 loads, 8B bf16x4 stores).
// ---------------------------------------------------------------------------
__global__ __launch_bounds__(256) void scan_x_kernel(
    const float* __restrict__ x, __hip_bfloat16* __restrict__ xs) {
  const int t  = blockIdx.x * 256 + threadIdx.x;   // 0..131071
  const int f4 = (t & 255) << 2;                   // feature start 0..1020
  const int c  = (t >> 8) & 7;                     // S-chunk 0..7 (block-uniform)
  const int b  = t >> 11;                          // batch 0..63
  const size_t base = (size_t)b * S_DIM * K_DIM + f4;
  const int s0 = c * 64;

  float4 h = {0.f, 0.f, 0.f, 0.f};
  if (c != 0) {                                    // block-uniform branch
    #pragma unroll 8
    for (int s = s0 - 32; s < s0; ++s) {
      float4 v = *(const float4*)(x + base + (size_t)s * K_DIM);
      h.x = 0.5f * (h.x + v.x); h.y = 0.5f * (h.y + v.y);
      h.z = 0.5f * (h.z + v.z); h.w = 0.5f * (h.w + v.w);
    }
  }
  #pragma unroll 8
  for (int s = s0; s < s0 + 64; ++s) {
    float4 v = *(const float4*)(x + base + (size_t)s * K_DIM);
    h.x = 0.5f * (h.x + v.x); h.y = 0.5f * (h.y + v.y);
    h.z = 0.5f * (h.z + v.z); h.w = 0.5f * (h.w + v.w);
    __hip_bfloat16 b0 = __float2bfloat16(h.x);
    __hip_bfloat16 b1 = __float2bfloat16(h.y);
    __hip_bfloat16 b2 = __float2bfloat16(h.z);
    __hip_bfloat16 b3 = __float2bfloat16(h.w);
    union { unsigned short u[4]; uint2 v2; } pk;
    pk.u[0] = *(unsigned short*)&b0; pk.u[1] = *(unsigned short*)&b1;
    pk.u[2] = *(unsigned short*)&b2; pk.u[3] = *(unsigned short*)&b3;
    *(uint2*)(xs + base + (size_t)s * K_DIM) = pk.v2;
  }
}

// ---------------------------------------------------------------------------
// Kernel 2: W fp32 -> bf16 (tiny: 1M elements)
// ---------------------------------------------------------------------------
__global__ __launch_bounds__(256) void conv_w_kernel(
    const float* __restrict__ W, __hip_bfloat16* __restrict__ Wb) {
  int t = blockIdx.x * 256 + threadIdx.x;
  Wb[t] = __float2bfloat16(W[t]);
}

// ---------------------------------------------------------------------------
// Kernel 3: bf16 NT GEMM, 128x128 tile, BK=32, 4 waves of 64x64.
// LDS k-chunk XOR swizzle: physical slot p holds logical k-chunk
// p ^ ((row>>1)&3). Applied on the GLOBAL source address at staging time
// (global_load_lds requires lane-contiguous LDS destinations) and inverted
// at ds_read time. Un-swizzled layout put 16 lanes on 8 banks (8-way
// conflict, 8.4M SQ_LDS_BANK_CONFLICT in R1); swizzled is 2-way = free.
// ---------------------------------------------------------------------------
__global__ __launch_bounds__(256) void gemm_kernel(
    const __hip_bfloat16* __restrict__ A,   // [M, K] scanned x
    const __hip_bfloat16* __restrict__ Bw,  // [N, K] W (torch Linear layout)
    float* __restrict__ out) {
  __shared__ __hip_bfloat16 lA[128 * 32];   // 8 KB
  __shared__ __hip_bfloat16 lB[128 * 32];   // 8 KB

  const int tid  = threadIdx.x;
  const int lane = tid & 63;
  const int w    = tid >> 6;        // wave 0..3
  const int wm   = (w >> 1) * 64;   // wave m offset within tile
  const int wn   = (w & 1) * 64;    // wave n offset within tile
  const int quad = lane >> 4;       // 0..3
  const int l15  = lane & 15;
  const int sw   = ((quad ^ ((l15 >> 1) & 3)) * 8);  // swizzled k-chunk offset

  const int n0 = blockIdx.x * 128;
  const int m0 = blockIdx.y * 128;

  floatx4 acc[4][4] = {};

  for (int k0 = 0; k0 < K_DIM; k0 += 32) {
    #pragma unroll
    for (int p = 0; p < 2; ++p) {
      int c    = tid + p * 256;     // 16-B chunk id 0..511
      int r    = c >> 2;            // tile row 0..127
      int slot = c & 3;             // physical k-slot in LDS row
      int kc   = (slot ^ ((r >> 1) & 3)) * 8;  // swizzled global k-chunk
      const __hip_bfloat16* ga = A  + (size_t)(m0 + r) * K_DIM + k0 + kc;
      const __hip_bfloat16* gb = Bw + (size_t)(n0 + r) * K_DIM + k0 + kc;
      __builtin_amdgcn_global_load_lds(
          (const __attribute__((address_space(1))) void*)ga,
          (__attribute__((address_space(3))) void*)&lA[c * 8], 16, 0, 0);
      __builtin_amdgcn_global_load_lds(
          (const __attribute__((address_space(1))) void*)gb,
          (__attribute__((address_space(3))) void*)&lB[c * 8], 16, 0, 0);
    }
    __syncthreads();

    // Fragment loads: logical chunk `quad` of row R is at physical slot
    // quad ^ ((R>>1)&3); (R>>1)&3 == (l15>>1)&3 since wm,i*16 are mult of 16.
    short8 af[4], bfr[4];
    #pragma unroll
    for (int i = 0; i < 4; ++i) {
      af[i]  = *(const short8*)&lA[(wm + i * 16 + l15) * 32 + sw];
      bfr[i] = *(const short8*)&lB[(wn + i * 16 + l15) * 32 + sw];
    }
    #pragma unroll
    for (int i = 0; i < 4; ++i)
      #pragma unroll
      for (int j = 0; j < 4; ++j)
        acc[i][j] = __builtin_amdgcn_mfma_f32_16x16x32_bf16(
            af[i], bfr[j], acc[i][j], 0, 0, 0);
    __syncthreads();
  }

  // Epilogue: C/D layout col=lane&15 (n), row=quad*4+reg (m)  [m89-verified]
  float* hid = out + B_DIM * N_DIM;  // hiddens after hk (65536 floats)
  #pragma unroll
  for (int i = 0; i < 4; ++i) {
    #pragma unroll
    for (int j = 0; j < 4; ++j) {
      #pragma unroll
      for (int r = 0; r < 4; ++r) {
        int gm = m0 + wm + i * 16 + quad * 4 + r;
        int gn = n0 + wn + j * 16 + l15;
        float v = acc[i][j][r];
        hid[(size_t)gm * N_DIM + gn] = v;
        if ((gm & (S_DIM - 1)) == (S_DIM - 1)) {     // s == 511 -> hk row
          out[(size_t)(gm >> 9) * N_DIM + gn] = v;   // hk[b, n]
        }
      }
    }
  }
}

extern "C" void kernel_launch(void* const* d_in, const int* in_sizes, int n_in,
                              void* d_out, int out_size, void* d_ws, size_t ws_size,
                              hipStream_t stream) {
  const float* x = (const float*)d_in[0];   // [64, 512, 1024] fp32
  const float* W = (const float*)d_in[1];   // [1024, 1024] fp32
  float* out = (float*)d_out;               // [65536 hk][33.55M hiddens] fp32

  __hip_bfloat16* xs = (__hip_bfloat16*)d_ws;
  __hip_bfloat16* Wb = (__hip_bfloat16*)((char*)d_ws + (size_t)M_DIM * K_DIM * 2);

  scan_x_kernel<<<dim3(131072 / 256), dim3(256), 0, stream>>>(x, xs);
  conv_w_kernel<<<dim3((N_DIM * K_DIM) / 256), dim3(256), 0, stream>>>(W, Wb);
  gemm_kernel<<<dim3(N_DIM / 128, M_DIM / 128), dim3(256), 0, stream>>>(xs, Wb, out);
}

// Round 3
// 334.275 us; speedup vs baseline: 1.0287x; 1.0287x over previous
//
#include <hip/hip_runtime.h>
#include <hip/hip_bf16.h>
#include <stdint.h>

#define B_DIM 64
#define S_DIM 512
#define K_DIM 1024   // F_IN
#define N_DIM 1024   // F_OUT
#define M_DIM (B_DIM * S_DIM)  // 32768

typedef __attribute__((ext_vector_type(8))) short short8;
typedef __attribute__((ext_vector_type(4))) float floatx4;

// ---------------------------------------------------------------------------
// Kernel 1: chunked EMA scan along S on x (fp32) fused with fp32->bf16.
// scan_S(x) @ W^T == scan_S(x @ W^T) (linearity). alpha=0.5 forgets at 0.5^k:
// 16-step warm-up restart is exact to ~1.5e-5 (vs 6.9e-2 threshold).
// S=512 in 16 chunks of 32 -> 262144 threads, 1024 blocks = 4 blocks/CU.
// ---------------------------------------------------------------------------
__global__ __launch_bounds__(256) void scan_x_kernel(
    const float* __restrict__ x, __hip_bfloat16* __restrict__ xs) {
  const int t  = blockIdx.x * 256 + threadIdx.x;   // 0..262143
  const int f4 = (t & 255) << 2;                   // feature start 0..1020
  const int c  = (t >> 8) & 15;                    // S-chunk 0..15 (block-uniform)
  const int b  = t >> 12;                          // batch 0..63
  const size_t base = (size_t)b * S_DIM * K_DIM + f4;
  const int s0 = c * 32;

  float4 h = {0.f, 0.f, 0.f, 0.f};
  if (c != 0) {                                    // block-uniform branch
    #pragma unroll 8
    for (int s = s0 - 16; s < s0; ++s) {
      float4 v = *(const float4*)(x + base + (size_t)s * K_DIM);
      h.x = 0.5f * (h.x + v.x); h.y = 0.5f * (h.y + v.y);
      h.z = 0.5f * (h.z + v.z); h.w = 0.5f * (h.w + v.w);
    }
  }
  #pragma unroll 8
  for (int s = s0; s < s0 + 32; ++s) {
    float4 v = *(const float4*)(x + base + (size_t)s * K_DIM);
    h.x = 0.5f * (h.x + v.x); h.y = 0.5f * (h.y + v.y);
    h.z = 0.5f * (h.z + v.z); h.w = 0.5f * (h.w + v.w);
    __hip_bfloat16 b0 = __float2bfloat16(h.x);
    __hip_bfloat16 b1 = __float2bfloat16(h.y);
    __hip_bfloat16 b2 = __float2bfloat16(h.z);
    __hip_bfloat16 b3 = __float2bfloat16(h.w);
    union { unsigned short u[4]; uint2 v2; } pk;
    pk.u[0] = *(unsigned short*)&b0; pk.u[1] = *(unsigned short*)&b1;
    pk.u[2] = *(unsigned short*)&b2; pk.u[3] = *(unsigned short*)&b3;
    *(uint2*)(xs + base + (size_t)s * K_DIM) = pk.v2;
  }
}

// ---------------------------------------------------------------------------
// Kernel 2: W fp32 -> bf16 (tiny: 1M elements)
// ---------------------------------------------------------------------------
__global__ __launch_bounds__(256) void conv_w_kernel(
    const float* __restrict__ W, __hip_bfloat16* __restrict__ Wb) {
  int t = blockIdx.x * 256 + threadIdx.x;
  Wb[t] = __float2bfloat16(W[t]);
}

// ---------------------------------------------------------------------------
// Kernel 3: bf16 NT GEMM, 128x128 tile, BK=64 (16 barriers instead of 32,
// 32 MFMA/wave/barrier -- AITER-style amortization), 4 waves of 64x64.
//
// XCD swizzle: block i -> xcd=i&7 (HW round-robin), each XCD owns a
// contiguous band of 32 m-tiles and iterates the 8 n-tiles fastest, so all
// 8 blocks sharing an A-tile live on ONE XCD's L2 (R2: FETCH 266 MB because
// sharers were spread across 8 XCDs, each refetching).
//
// LDS swizzle: physical k-slot = logical ^ (row&7), applied to the GLOBAL
// source address at staging (global_load_lds needs lane-contiguous LDS dest)
// and inverted at ds_read. Row stride 128 B == 0 mod 32 banks; each lane
// octet covers all 8 bank-quads -> conflict-free (R2 measured 0 with the
// BK=32 version of this construction).
// ---------------------------------------------------------------------------
__global__ __launch_bounds__(256) void gemm_kernel(
    const __hip_bfloat16* __restrict__ A,   // [M, K] scanned x
    const __hip_bfloat16* __restrict__ Bw,  // [N, K] W (torch Linear layout)
    float* __restrict__ out) {
  __shared__ __hip_bfloat16 lA[128 * 64];   // 16 KB
  __shared__ __hip_bfloat16 lB[128 * 64];   // 16 KB

  const int tid  = threadIdx.x;
  const int lane = tid & 63;
  const int w    = tid >> 6;        // wave 0..3
  const int wm   = (w >> 1) * 64;   // wave m offset within tile
  const int wn   = (w & 1) * 64;    // wave n offset within tile
  const int quad = lane >> 4;       // 0..3
  const int l15  = lane & 15;
  const int r7   = l15 & 7;         // == (fragment row) & 7 (wm, i*16 are mult of 8)

  const int bi    = blockIdx.x;     // 0..2047
  const int xcd   = bi & 7;
  const int local = bi >> 3;        // 0..255
  const int m0 = (xcd * 32 + (local >> 3)) * 128;
  const int n0 = (local & 7) * 128;

  floatx4 acc[4][4] = {};

  for (int k0 = 0; k0 < K_DIM; k0 += 64) {
    #pragma unroll
    for (int p = 0; p < 4; ++p) {
      int c    = tid + p * 256;     // 16-B chunk id 0..1023
      int r    = c >> 3;            // tile row 0..127
      int slot = c & 7;             // physical k-slot in LDS row
      int kc   = (slot ^ (r & 7)) * 8;  // swizzled global k-chunk (bf16 elems)
      const __hip_bfloat16* ga = A  + (size_t)(m0 + r) * K_DIM + k0 + kc;
      const __hip_bfloat16* gb = Bw + (size_t)(n0 + r) * K_DIM + k0 + kc;
      __builtin_amdgcn_global_load_lds(
          (const __attribute__((address_space(1))) void*)ga,
          (__attribute__((address_space(3))) void*)&lA[c * 8], 16, 0, 0);
      __builtin_amdgcn_global_load_lds(
          (const __attribute__((address_space(1))) void*)gb,
          (__attribute__((address_space(3))) void*)&lB[c * 8], 16, 0, 0);
    }
    __syncthreads();

    #pragma unroll
    for (int kk = 0; kk < 64; kk += 32) {
      const int q0 = kk >> 3;       // logical chunk base for this sub-step
      short8 af[4], bfr[4];
      #pragma unroll
      for (int i = 0; i < 4; ++i) {
        af[i]  = *(const short8*)&lA[(wm + i * 16 + l15) * 64 +
                                     (((q0 + quad) ^ r7) * 8)];
        bfr[i] = *(const short8*)&lB[(wn + i * 16 + l15) * 64 +
                                     (((q0 + quad) ^ r7) * 8)];
      }
      #pragma unroll
      for (int i = 0; i < 4; ++i)
        #pragma unroll
        for (int j = 0; j < 4; ++j)
          acc[i][j] = __builtin_amdgcn_mfma_f32_16x16x32_bf16(
              af[i], bfr[j], acc[i][j], 0, 0, 0);
    }
    __syncthreads();
  }

  // Epilogue: C/D layout col=lane&15 (n), row=quad*4+reg (m)  [m89-verified]
  float* hid = out + B_DIM * N_DIM;  // hiddens after hk (65536 floats)
  #pragma unroll
  for (int i = 0; i < 4; ++i) {
    #pragma unroll
    for (int j = 0; j < 4; ++j) {
      #pragma unroll
      for (int r = 0; r < 4; ++r) {
        int gm = m0 + wm + i * 16 + quad * 4 + r;
        int gn = n0 + wn + j * 16 + l15;
        float v = acc[i][j][r];
        hid[(size_t)gm * N_DIM + gn] = v;
        if ((gm & (S_DIM - 1)) == (S_DIM - 1)) {     // s == 511 -> hk row
          out[(size_t)(gm >> 9) * N_DIM + gn] = v;   // hk[b, n]
        }
      }
    }
  }
}

extern "C" void kernel_launch(void* const* d_in, const int* in_sizes, int n_in,
                              void* d_out, int out_size, void* d_ws, size_t ws_size,
                              hipStream_t stream) {
  const float* x = (const float*)d_in[0];   // [64, 512, 1024] fp32
  const float* W = (const float*)d_in[1];   // [1024, 1024] fp32
  float* out = (float*)d_out;               // [65536 hk][33.55M hiddens] fp32

  __hip_bfloat16* xs = (__hip_bfloat16*)d_ws;
  __hip_bfloat16* Wb = (__hip_bfloat16*)((char*)d_ws + (size_t)M_DIM * K_DIM * 2);

  scan_x_kernel<<<dim3(262144 / 256), dim3(256), 0, stream>>>(x, xs);
  conv_w_kernel<<<dim3((N_DIM * K_DIM) / 256), dim3(256), 0, stream>>>(W, Wb);
  gemm_kernel<<<dim3((M_DIM / 128) * (N_DIM / 128)), dim3(256), 0, stream>>>(xs, Wb, out);
}